// Round 9
// baseline (218.881 us; speedup 1.0000x reference)
//
#include <hip/hip_runtime.h>
#include <hip/hip_bf16.h>
#include <stdint.h>

// Problem dims (fixed by reference)
#define HH 224
#define WW 224
#define CC 1024
#define BB 256
#define KK (HH*WW)            // 50176
#define EPSILON_F 0.001f
#define LOG2E 1.4426950408889634f
#define INVN (1.0f/50176.0f)
// clip(v,+-2000)/N == clip(v/N, +-2000/N) since 1/N > 0
#define CLAMP_V (2000.0f/50176.0f)

// R9: ZERO-BARRIER hybrid.
//   R8 evidence: LDS-pipe + per-step barrier bound (9 LDS b128/wave-step for 8 MFMAs,
//   1020 cyc/step-slot vs 310 MFMA). Fix by operand:
//   - B (curves) is COMPUTED -> per-lane register gen (R7-verified layout), no LDS, no dup
//     through memory at all.
//   - A needs COALESCING, not sharing (each A row feeds exactly one wave) -> wave-private
//     LDS transpose: wave loads its own 64 rows as 64-B segments (4x uint4/lane), writes its
//     own LDS slice, reads fragments back. No cross-wave dependency -> NO __syncthreads
//     anywhere. In-wave lgkmcnt ordering is sufficient. Avoids R5/R7's per-lane gather.
//   Tile: 256m x 64c per block (4 waves x 64m x 64c, 16 MFMAs per 4 LDS reads).
//   grid = 16c x 56z = 896 blocks, XCD swizzle (R5-proven), bf16 A (3.2 MB/XCD: L2-resident
//   even without barrier lockstep). Atomic epilogue (R5/R6: >= stores+reduce).
#define KCHUNKS 56
#define ROWS_PER_CHUNK 4
#define WBS 7                 // 224/32 k-blocks per image row

// 36 elems = 72 B rows: near-uniform bank spread for both staging writes and b128 frag reads
#define LDS_STRIDE 36
#define WSLICE (64 * LDS_STRIDE)   // one wave's single-buffer slice (elems)

typedef __bf16 bf16x8 __attribute__((ext_vector_type(8)));
typedef float  f32x4  __attribute__((ext_vector_type(4)));

// ---------------- prepass: x fp32 -> bf16 -------------------------------------------------
__global__ __launch_bounds__(256)
void cvt_bf16_kernel(const float* __restrict__ x, __hip_bfloat16* __restrict__ xb, int n8) {
    int i = blockIdx.x * 256 + threadIdx.x;   // one thread per 8 elements
    if (i >= n8) return;
    const float4* p = (const float4*)(x + (size_t)i * 8);
    float4 a = p[0], b = p[1];
    union { __hip_bfloat16 h[8]; uint4 u; } o;
    o.h[0] = (__hip_bfloat16)a.x; o.h[1] = (__hip_bfloat16)a.y;
    o.h[2] = (__hip_bfloat16)a.z; o.h[3] = (__hip_bfloat16)a.w;
    o.h[4] = (__hip_bfloat16)b.x; o.h[5] = (__hip_bfloat16)b.y;
    o.h[6] = (__hip_bfloat16)b.z; o.h[7] = (__hip_bfloat16)b.w;
    *(uint4*)(xb + (size_t)i * 8) = o.u;
}

// ---------------- main fused curve-gen + GEMM ---------------------------------------------
// NOTE: no min-waves arg in __launch_bounds__ (R2: (256,7) spilled the accumulator).
template <bool BF16A>
__global__ __launch_bounds__(256)
void blob_gemm_kernel(const void* __restrict__ xin,
                      const float* __restrict__ pos,
                      const float* __restrict__ sig,
                      const float* __restrict__ cwt,
                      const float* __restrict__ xs,
                      const float* __restrict__ ys,
                      float* __restrict__ out) {
    // [buf][wave slice]: wave-private staging, double-buffered
    __shared__ __bf16 As[2][4 * WSLICE];

    const int tid  = threadIdx.x;
    const int wave = tid >> 6;
    const int lane = tid & 63;

    // XCD-locality swizzle (R5/R6/R8 proven): xcd = id%8 owns k-chunks [xcd*7, xcd*7+7).
    const int id   = blockIdx.x;
    const int xcd  = id & 7;
    const int slot = id >> 3;                  // 0..111
    const int z    = xcd * 7 + slot % 7;       // k-chunk 0..55
    const int cx   = slot / 7;                 // c-tile 0..15
    const int c0   = cx * 64;
    const int k0   = z * (ROWS_PER_CHUNK * WW);

    // fragment lane mapping: op[row = lane&15][k = (lane>>4)*8 + j]
    const int fl = lane & 15;
    const int fk = (lane >> 4) * 8;
    const int wm = wave * 64;                  // this wave's 64 m-rows

    // ---- per-lane B params for its 4 c's: c = c0 + ni*16 + fl (R7-verified layout) ----
    float A2[4], S2[4], P0[4], P1[4];
#pragma unroll
    for (int ni = 0; ni < 4; ++ni) {
        int c = c0 + ni * 16 + fl;
        float s  = sig[c];
        float w  = cwt[c];
        float s2 = s * s;
        A2[ni] = w / (6.283185307179586f * s2 + EPSILON_F) * INVN;
        S2[ni] = LOG2E / (2.0f * s2 + EPSILON_F);
        P0[ni] = pos[2 * c];
        P1[ni] = pos[2 * c + 1];
    }

    // y-axis values for this chunk's 4 rows (broadcast loads, L2/L3-resident)
    float ycolr[ROWS_PER_CHUNK];
#pragma unroll
    for (int r = 0; r < ROWS_PER_CHUNK; ++r) ycolr[r] = ys[(size_t)(z * ROWS_PER_CHUNK + r) * WW];

    // ---- wave-private A staging: round j stages local rows 16j+(lane>>2), k-octet lane&3 ----
    const int lr = lane >> 2;       // 0..15
    const int o  = lane & 3;        // k-octet
    const __hip_bfloat16* sgb = (const __hip_bfloat16*)xin + (size_t)(wm + 16 * 0 + lr) * KK + k0 + o * 8;
    const float*          sgf = (const float*)xin          + (size_t)(wm + lr) * KK + k0 + o * 8;
    const int sw_off = lr * LDS_STRIDE + o * 8;         // + 16j*LDS_STRIDE per round
    const int ar_off = fl * LDS_STRIDE + fk;            // + mi*16*LDS_STRIDE per frag
    __bf16* wbase0 = &As[0][wave * WSLICE];
    __bf16* wbase1 = &As[1][wave * WSLICE];

    auto cvt8 = [](float4 f0, float4 f1) -> uint4 {
        union { __bf16 h[8]; uint4 u; } t;
        t.h[0] = (__bf16)f0.x; t.h[1] = (__bf16)f0.y;
        t.h[2] = (__bf16)f0.z; t.h[3] = (__bf16)f0.w;
        t.h[4] = (__bf16)f1.x; t.h[5] = (__bf16)f1.y;
        t.h[6] = (__bf16)f1.z; t.h[7] = (__bf16)f1.w;
        return t.u;
    };

    auto load_stage = [&](int koff, uint4 pa[4]) {
        if (BF16A) {
#pragma unroll
            for (int j = 0; j < 4; ++j)
                pa[j] = *(const uint4*)(sgb + (size_t)(16 * j) * KK + koff);
        } else {
#pragma unroll
            for (int j = 0; j < 4; ++j) {
                const float* p = sgf + (size_t)(16 * j) * KK + koff;
                pa[j] = cvt8(*(const float4*)p, *(const float4*)(p + 4));
            }
        }
    };
    auto write_stage = [&](__bf16* wb, const uint4 pa[4]) {
#pragma unroll
        for (int j = 0; j < 4; ++j)
            *(uint4*)(wb + 16 * j * LDS_STRIDE + sw_off) = pa[j];
    };

    // ---- ExA cache: exp2(-dx^2*S2)*A2 for this lane's 8 k-positions x 4 c's (per wb) ----
    float ExA[4][8];
    auto refresh_ex = [&](int wb) {
        float4 xa = *(const float4*)(xs + wb * 32 + fk);
        float4 xbv = *(const float4*)(xs + wb * 32 + fk + 4);
        float xv[8] = {xa.x, xa.y, xa.z, xa.w, xbv.x, xbv.y, xbv.z, xbv.w};
#pragma unroll
        for (int ni = 0; ni < 4; ++ni)
#pragma unroll
            for (int j = 0; j < 8; ++j) {
                float dx = xv[j] - P1[ni];
                ExA[ni][j] = __builtin_amdgcn_exp2f(-(dx * S2[ni] * dx)) * A2[ni];
            }
    };

    f32x4 acc[4][4];
#pragma unroll
    for (int i = 0; i < 4; ++i)
#pragma unroll
        for (int j = 0; j < 4; ++j) acc[i][j] = (f32x4){0.f, 0.f, 0.f, 0.f};

    // ---- prologue: stage step 0 into buf 0 ----
    {
        uint4 pa[4];
        load_stage(0, pa);
        write_stage(wbase0, pa);
    }

    // ---- zero-barrier main loop: 7 wb x 4 r steps ----
#pragma unroll 1
    for (int wb = 0; wb < WBS; ++wb) {
        refresh_ex(wb);
#pragma unroll
        for (int r = 0; r < ROWS_PER_CHUNK; ++r) {
            const int s  = wb * ROWS_PER_CHUNK + r;
            const int cb = s & 1;
            const bool last = (s == WBS * ROWS_PER_CHUNK - 1);

            // 1. issue next step's staging loads (longest latency first)
            uint4 pa[4];
            if (!last) {
                int nr = r + 1, nwb = wb;
                if (nr == ROWS_PER_CHUNK) { nr = 0; ++nwb; }
                load_stage(nr * WW + nwb * 32, pa);
            }

            // 2. A fragments from this wave's LDS slice (staged last step)
            __bf16* rb = cb ? wbase1 : wbase0;
            bf16x8 fa[4];
#pragma unroll
            for (int mi = 0; mi < 4; ++mi)
                fa[mi] = *(const bf16x8*)(rb + ar_off + mi * 16 * LDS_STRIDE);

            // 3. generate B per-ni in registers and run its 4 MFMAs (keeps fb live-range 1)
            const float ysv = ycolr[r];
#pragma unroll
            for (int ni = 0; ni < 4; ++ni) {
                float dy = ysv - P0[ni];
                float ey = __builtin_amdgcn_exp2f(-(dy * S2[ni] * dy));
                union { __bf16 h[8]; bf16x8 v; } t;
#pragma unroll
                for (int j = 0; j < 8; ++j) {
                    float v = ExA[ni][j] * ey;
                    t.h[j] = (__bf16)__builtin_amdgcn_fmed3f(v, -CLAMP_V, CLAMP_V);
                }
#pragma unroll
                for (int mi = 0; mi < 4; ++mi)
                    acc[mi][ni] = __builtin_amdgcn_mfma_f32_16x16x32_bf16(
                        fa[mi], t.v, acc[mi][ni], 0, 0, 0);
            }

            // 4. write next step's staging into the other buffer (wave-private: no barrier)
            if (!last) write_stage(cb ? wbase0 : wbase1, pa);
        }
    }

    // ---- epilogue: C/D layout col=lane&15, row=(lane>>4)*4+reg -> atomicAdd (K-split) ----
    const int orow = (lane >> 4) * 4;
#pragma unroll
    for (int mi = 0; mi < 4; ++mi) {
        int m = wm + mi * 16 + orow;
#pragma unroll
        for (int ni = 0; ni < 4; ++ni) {
            int cc = c0 + ni * 16 + fl;
#pragma unroll
            for (int v = 0; v < 4; ++v)
                atomicAdd(out + (size_t)(m + v) * CC + cc, acc[mi][ni][v]);
        }
    }
}

extern "C" void kernel_launch(void* const* d_in, const int* in_sizes, int n_in,
                              void* d_out, int out_size, void* d_ws, size_t ws_size,
                              hipStream_t stream) {
    const float* x   = (const float*)d_in[0];
    const float* pos = (const float*)d_in[1];
    const float* sg  = (const float*)d_in[2];
    const float* cw  = (const float*)d_in[3];
    const float* xs  = (const float*)d_in[4];
    const float* ys  = (const float*)d_in[5];
    float* out = (float*)d_out;

    // K-split partials accumulate via atomicAdd -> zero output first
    hipMemsetAsync(out, 0, (size_t)BB * CC * sizeof(float), stream);

    const int nblk = 16 * KCHUNKS;                   // 896
    const size_t nx = (size_t)BB * KK;
    const size_t XB = nx * sizeof(__hip_bfloat16);   // 25.7 MB

    if (ws_size >= XB) {
        __hip_bfloat16* xb = (__hip_bfloat16*)d_ws;
        int n8 = (int)(nx / 8);
        cvt_bf16_kernel<<<(n8 + 255) / 256, 256, 0, stream>>>(x, xb, n8);
        blob_gemm_kernel<true><<<nblk, 256, 0, stream>>>(xb, pos, sg, cw, xs, ys, out);
    } else {
        blob_gemm_kernel<false><<<nblk, 256, 0, stream>>>(x, pos, sg, cw, xs, ys, out);
    }
}